// Round 4
// baseline (361.506 us; speedup 1.0000x reference)
//
#include <hip/hip_runtime.h>

#define NN 50000
#define NE 800000
#define DIN 128
#define DHID 256
#define MAXDEG 128   // Binomial(800k,1/50k): mean 16, sigma 4; 128 = 28 sigma

typedef __bf16 bf16x8 __attribute__((ext_vector_type(8)));
typedef float f32x4 __attribute__((ext_vector_type(4)));

static __device__ __forceinline__ unsigned short f2bf(float f) {
    unsigned u = __float_as_uint(f);
    unsigned r = 0x7fffu + ((u >> 16) & 1u);
    return (unsigned short)((u + r) >> 16);
}
static __device__ __forceinline__ float blo(unsigned u) { return __uint_as_float(u << 16); }
static __device__ __forceinline__ float bhi(unsigned u) { return __uint_as_float(u & 0xffff0000u); }

// ---------------- bucket build (fixed-stride buckets, x8 edge ILP) ----------------

__global__ void bucket_kernel(const int* __restrict__ src, const int* __restrict__ dst,
                              int* __restrict__ cnt, int* __restrict__ srcs, int E) {
    int i8 = (blockIdx.x * blockDim.x + threadIdx.x) * 8;
    if (i8 >= E) return;
    int4 da = *(const int4*)&dst[i8];
    int4 db = *(const int4*)&dst[i8 + 4];
    int4 sa = *(const int4*)&src[i8];
    int4 sb = *(const int4*)&src[i8 + 4];
    int t0 = atomicAdd(&cnt[da.x], 1);
    int t1 = atomicAdd(&cnt[da.y], 1);
    int t2 = atomicAdd(&cnt[da.z], 1);
    int t3 = atomicAdd(&cnt[da.w], 1);
    int t4 = atomicAdd(&cnt[db.x], 1);
    int t5 = atomicAdd(&cnt[db.y], 1);
    int t6 = atomicAdd(&cnt[db.z], 1);
    int t7 = atomicAdd(&cnt[db.w], 1);
    if (t0 < MAXDEG) srcs[(size_t)da.x * MAXDEG + t0] = sa.x;
    if (t1 < MAXDEG) srcs[(size_t)da.y * MAXDEG + t1] = sa.y;
    if (t2 < MAXDEG) srcs[(size_t)da.z * MAXDEG + t2] = sa.z;
    if (t3 < MAXDEG) srcs[(size_t)da.w * MAXDEG + t3] = sa.w;
    if (t4 < MAXDEG) srcs[(size_t)db.x * MAXDEG + t4] = sb.x;
    if (t5 < MAXDEG) srcs[(size_t)db.y * MAXDEG + t5] = sb.y;
    if (t6 < MAXDEG) srcs[(size_t)db.z * MAXDEG + t6] = sb.z;
    if (t7 < MAXDEG) srcs[(size_t)db.w * MAXDEG + t7] = sb.w;
}

// ---------------- prep: x fp32->bf16, zero cnt[], all 5 weights fp32->bf16 transposed ----------------

__global__ void prep_kernel(const float* __restrict__ x, unsigned short* __restrict__ xb,
                            int* __restrict__ cnt,
                            const float* __restrict__ W1_0, const float* __restrict__ W2_0,
                            const float* __restrict__ W1_1, const float* __restrict__ W2_1,
                            const float* __restrict__ Wo,
                            unsigned short* __restrict__ w10t, unsigned short* __restrict__ w20t,
                            unsigned short* __restrict__ w11t, unsigned short* __restrict__ w21t,
                            unsigned short* __restrict__ wot) {
    int i = blockIdx.x * blockDim.x + threadIdx.x;
    if (i < NN) cnt[i] = 0;
    if (i < 262144) {
        const float* W; unsigned short* Wt; int K, N, idx;
        if (i < 32768)        { W = W1_0; Wt = w10t; K = 128; N = 256; idx = i; }
        else if (i < 98304)   { W = W2_0; Wt = w20t; K = 256; N = 256; idx = i - 32768; }
        else if (i < 163840)  { W = W1_1; Wt = w11t; K = 256; N = 256; idx = i - 98304; }
        else if (i < 229376)  { W = W2_1; Wt = w21t; K = 256; N = 256; idx = i - 163840; }
        else                  { W = Wo;   Wt = wot;  K = 256; N = 128; idx = i - 229376; }
        int k = idx / N;
        int n = idx - k * N;
        Wt[(size_t)n * K + k] = f2bf(W[idx]);
    }
    if (i * 4 < NN * DIN) {
        float4 v = *(const float4*)(x + (size_t)i * 4);
        ushort4 o;
        o.x = f2bf(v.x); o.y = f2bf(v.y); o.z = f2bf(v.z); o.w = f2bf(v.w);
        *(ushort4*)(xb + (size_t)i * 4) = o;
    }
}

// ---------------- aggregation: multi-node per wave, 16B gathers, 8-deep MLP ----------------
// D=128: 4 nodes/wave (16 lanes x uint4 = 256B row); D=256: 2 nodes/wave (32 x uint4).
// out[n] = (1+eps)*x[n] + sum_{s in N(n)} x[s]; fp32 accum.

template <int D>
__global__ void agg_bf16_kernel(const unsigned short* __restrict__ x, const int* __restrict__ cnt,
                                const int* __restrict__ srcs, const float* __restrict__ eps_p,
                                unsigned short* __restrict__ out, int n) {
    constexpr int G = (D == 128) ? 4 : 2;   // nodes per wave
    constexpr int L = 64 / G;               // lanes per node
    constexpr int RQ = D / 8;               // uint4 per row
    int tid = blockIdx.x * blockDim.x + threadIdx.x;
    int wid = tid >> 6;
    int lane = threadIdx.x & 63;
    int group = lane / L;
    int li = lane % L;
    int node = wid * G + group;
    if (node >= n) return;
    int deg = cnt[node]; if (deg > MAXDEG) deg = MAXDEG;
    const int* sp = srcs + (size_t)node * MAXDEG;
    const uint4* xp = (const uint4*)x;
    float e = 1.0f + eps_p[0];

    float a[8], b[8];
    #pragma unroll
    for (int j = 0; j < 8; j++) { a[j] = 0.f; b[j] = 0.f; }

    int i = 0;
    for (; i + 8 <= deg; i += 8) {
        int4 s0 = *(const int4*)&sp[i];
        int4 s1 = *(const int4*)&sp[i + 4];
        uint4 v0 = xp[(size_t)s0.x * RQ + li];
        uint4 v1 = xp[(size_t)s0.y * RQ + li];
        uint4 v2 = xp[(size_t)s0.z * RQ + li];
        uint4 v3 = xp[(size_t)s0.w * RQ + li];
        uint4 v4 = xp[(size_t)s1.x * RQ + li];
        uint4 v5 = xp[(size_t)s1.y * RQ + li];
        uint4 v6 = xp[(size_t)s1.z * RQ + li];
        uint4 v7 = xp[(size_t)s1.w * RQ + li];
        a[0] += blo(v0.x); a[1] += bhi(v0.x); a[2] += blo(v0.y); a[3] += bhi(v0.y);
        a[4] += blo(v0.z); a[5] += bhi(v0.z); a[6] += blo(v0.w); a[7] += bhi(v0.w);
        b[0] += blo(v1.x); b[1] += bhi(v1.x); b[2] += blo(v1.y); b[3] += bhi(v1.y);
        b[4] += blo(v1.z); b[5] += bhi(v1.z); b[6] += blo(v1.w); b[7] += bhi(v1.w);
        a[0] += blo(v2.x); a[1] += bhi(v2.x); a[2] += blo(v2.y); a[3] += bhi(v2.y);
        a[4] += blo(v2.z); a[5] += bhi(v2.z); a[6] += blo(v2.w); a[7] += bhi(v2.w);
        b[0] += blo(v3.x); b[1] += bhi(v3.x); b[2] += blo(v3.y); b[3] += bhi(v3.y);
        b[4] += blo(v3.z); b[5] += bhi(v3.z); b[6] += blo(v3.w); b[7] += bhi(v3.w);
        a[0] += blo(v4.x); a[1] += bhi(v4.x); a[2] += blo(v4.y); a[3] += bhi(v4.y);
        a[4] += blo(v4.z); a[5] += bhi(v4.z); a[6] += blo(v4.w); a[7] += bhi(v4.w);
        b[0] += blo(v5.x); b[1] += bhi(v5.x); b[2] += blo(v5.y); b[3] += bhi(v5.y);
        b[4] += blo(v5.z); b[5] += bhi(v5.z); b[6] += blo(v5.w); b[7] += bhi(v5.w);
        a[0] += blo(v6.x); a[1] += bhi(v6.x); a[2] += blo(v6.y); a[3] += bhi(v6.y);
        a[4] += blo(v6.z); a[5] += bhi(v6.z); a[6] += blo(v6.w); a[7] += bhi(v6.w);
        b[0] += blo(v7.x); b[1] += bhi(v7.x); b[2] += blo(v7.y); b[3] += bhi(v7.y);
        b[4] += blo(v7.z); b[5] += bhi(v7.z); b[6] += blo(v7.w); b[7] += bhi(v7.w);
    }
    for (; i + 4 <= deg; i += 4) {
        int4 s = *(const int4*)&sp[i];
        uint4 v0 = xp[(size_t)s.x * RQ + li];
        uint4 v1 = xp[(size_t)s.y * RQ + li];
        uint4 v2 = xp[(size_t)s.z * RQ + li];
        uint4 v3 = xp[(size_t)s.w * RQ + li];
        a[0] += blo(v0.x); a[1] += bhi(v0.x); a[2] += blo(v0.y); a[3] += bhi(v0.y);
        a[4] += blo(v0.z); a[5] += bhi(v0.z); a[6] += blo(v0.w); a[7] += bhi(v0.w);
        b[0] += blo(v1.x); b[1] += bhi(v1.x); b[2] += blo(v1.y); b[3] += bhi(v1.y);
        b[4] += blo(v1.z); b[5] += bhi(v1.z); b[6] += blo(v1.w); b[7] += bhi(v1.w);
        a[0] += blo(v2.x); a[1] += bhi(v2.x); a[2] += blo(v2.y); a[3] += bhi(v2.y);
        a[4] += blo(v2.z); a[5] += bhi(v2.z); a[6] += blo(v2.w); a[7] += bhi(v2.w);
        b[0] += blo(v3.x); b[1] += bhi(v3.x); b[2] += blo(v3.y); b[3] += bhi(v3.y);
        b[4] += blo(v3.z); b[5] += bhi(v3.z); b[6] += blo(v3.w); b[7] += bhi(v3.w);
    }
    for (; i < deg; i++) {
        uint4 v = xp[(size_t)sp[i] * RQ + li];
        a[0] += blo(v.x); a[1] += bhi(v.x); a[2] += blo(v.y); a[3] += bhi(v.y);
        a[4] += blo(v.z); a[5] += bhi(v.z); a[6] += blo(v.w); a[7] += bhi(v.w);
    }
    uint4 xv = xp[(size_t)node * RQ + li];
    a[0] += b[0] + e * blo(xv.x); a[1] += b[1] + e * bhi(xv.x);
    a[2] += b[2] + e * blo(xv.y); a[3] += b[3] + e * bhi(xv.y);
    a[4] += b[4] + e * blo(xv.z); a[5] += b[5] + e * bhi(xv.z);
    a[6] += b[6] + e * blo(xv.w); a[7] += b[7] + e * bhi(xv.w);
    uint4 o;
    o.x = (unsigned)f2bf(a[0]) | ((unsigned)f2bf(a[1]) << 16);
    o.y = (unsigned)f2bf(a[2]) | ((unsigned)f2bf(a[3]) << 16);
    o.z = (unsigned)f2bf(a[4]) | ((unsigned)f2bf(a[5]) << 16);
    o.w = (unsigned)f2bf(a[6]) | ((unsigned)f2bf(a[7]) << 16);
    ((uint4*)out)[(size_t)node * RQ + li] = o;
}

// ---------------- fused MLP v5: 64-row tiles, 4 waves, A-tile register prefetch ----------------
// R1/R3 post-mortem: raising occupancy (smaller tiles / more waves) REGRESSED both
// times -> not wave-starved; per-wave latency exposure is the limiter. FETCH_SIZE
// 13.9MB == the A stream (bufA evicted from 4MiB/XCD L2 between kernels), so phase-1
// A loads are ~900cy HBM misses issued only 4-8 deep inside the K-loop. v5: (1) burst-
// prefetch the ENTIRE per-wave A tile into registers (16/32 x global_load_dwordx4,
// one latency for the burst) before phase 1; (2) unroll 4 on W-stream loops (deeper
// L2 pipeline). VGPR ~100->~170 is free: occupancy is grid-limited (782 blocks -> 3
// waves/SIMD max). Load-order-only change => bit-identical numerics.
// C = [relu(A@W1+b1)@W2+b2] (@Wo+bo if THREE). Weights pre-transposed [N][K] bf16,
// L2-resident. acc[4][4] across full K. Single 32KB H buffer; THREE defers phase-2
// epilogue in acc until one barrier, then overwrites H in place. MFMA swapped
// operands (bw, af): lane = C-row l16, regs = 4 consecutive C-cols. XOR chunk swizzle.

template <int K1, int THREE>
__global__ __launch_bounds__(256) void mlp_fused(
        const unsigned short* __restrict__ A,
        const unsigned short* __restrict__ W1t, const float* __restrict__ b1,
        const unsigned short* __restrict__ W2t, const float* __restrict__ b2,
        const unsigned short* __restrict__ W3t, const float* __restrict__ b3,
        unsigned short* __restrict__ Cb, float* __restrict__ Cf, int M) {
    constexpr int NKS1 = K1 / 32;
    __shared__ __align__(16) unsigned short H[64 * 256];   // 32KB

    const int lane = threadIdx.x & 63;
    const int w = threadIdx.x >> 6;      // n-slice
    const int quad = lane >> 4;
    const int l16 = lane & 15;
    const size_t rowbase = (size_t)blockIdx.x * 64;

    // ---- A-tile burst prefetch: all phase-1 fragments, one deep pipeline ----
    bf16x8 afr[NKS1][4];
    #pragma unroll
    for (int ks = 0; ks < NKS1; ks++)
        #pragma unroll
        for (int j = 0; j < 4; j++)
            afr[ks][j] = *(const bf16x8*)&A[(rowbase + j * 16 + l16) * K1 + ks * 32 + quad * 8];

    f32x4 acc[4][4];

    // ---- phase 1: acc = A @ W1 (A in regs, stream W1) ----
    #pragma unroll
    for (int j = 0; j < 4; j++)
        #pragma unroll
        for (int nt = 0; nt < 4; nt++) acc[j][nt] = (f32x4)(0.f);
    #pragma unroll 4
    for (int ks = 0; ks < NKS1; ks++) {
        bf16x8 bw[4];
        #pragma unroll
        for (int nt = 0; nt < 4; nt++)
            bw[nt] = *(const bf16x8*)&W1t[(size_t)(w * 64 + nt * 16 + l16) * K1 + ks * 32 + quad * 8];
        #pragma unroll
        for (int j = 0; j < 4; j++) {
            #pragma unroll
            for (int nt = 0; nt < 4; nt++)
                acc[j][nt] = __builtin_amdgcn_mfma_f32_16x16x32_bf16(bw[nt], afr[ks][j], acc[j][nt], 0, 0, 0);
        }
    }
    {   // epilogue 1: bias + relu -> H (swizzled)
        f32x4 bvv[4];
        #pragma unroll
        for (int nt = 0; nt < 4; nt++)
            bvv[nt] = *(const f32x4*)&b1[w * 64 + nt * 16 + quad * 4];
        #pragma unroll
        for (int j = 0; j < 4; j++) {
            int r = j * 16 + l16;
            #pragma unroll
            for (int nt = 0; nt < 4; nt++) {
                f32x4 v = acc[j][nt] + bvv[nt];
                v[0] = fmaxf(v[0], 0.f); v[1] = fmaxf(v[1], 0.f);
                v[2] = fmaxf(v[2], 0.f); v[3] = fmaxf(v[3], 0.f);
                int c = w * 8 + nt * 2 + (quad >> 1);
                int cs = c ^ (r & 7);
                uint2 o;
                o.x = (unsigned)f2bf(v[0]) | ((unsigned)f2bf(v[1]) << 16);
                o.y = (unsigned)f2bf(v[2]) | ((unsigned)f2bf(v[3]) << 16);
                *(uint2*)&H[r * 256 + cs * 8 + (quad & 1) * 4] = o;
            }
        }
    }
    __syncthreads();

    // ---- phase 2: acc = H @ W2 (stream W2, K=256) ----
    #pragma unroll
    for (int j = 0; j < 4; j++)
        #pragma unroll
        for (int nt = 0; nt < 4; nt++) acc[j][nt] = (f32x4)(0.f);
    #pragma unroll 4
    for (int ks = 0; ks < 8; ks++) {
        bf16x8 bw[4];
        #pragma unroll
        for (int nt = 0; nt < 4; nt++)
            bw[nt] = *(const bf16x8*)&W2t[(size_t)(w * 64 + nt * 16 + l16) * 256 + ks * 32 + quad * 8];
        #pragma unroll
        for (int j = 0; j < 4; j++) {
            int r = j * 16 + l16;
            int cs = (ks * 4 + quad) ^ (r & 7);
            bf16x8 af = *(const bf16x8*)&H[r * 256 + cs * 8];
            #pragma unroll
            for (int nt = 0; nt < 4; nt++)
                acc[j][nt] = __builtin_amdgcn_mfma_f32_16x16x32_bf16(bw[nt], af, acc[j][nt], 0, 0, 0);
        }
    }
    {
        f32x4 bvv[4];
        #pragma unroll
        for (int nt = 0; nt < 4; nt++)
            bvv[nt] = *(const f32x4*)&b2[w * 64 + nt * 16 + quad * 4];
        if constexpr (!THREE) {
            #pragma unroll
            for (int j = 0; j < 4; j++) {
                size_t gm = rowbase + j * 16 + l16;
                if (gm < (size_t)M) {
                    #pragma unroll
                    for (int nt = 0; nt < 4; nt++) {
                        f32x4 v = acc[j][nt] + bvv[nt];
                        uint2 o;
                        o.x = (unsigned)f2bf(v[0]) | ((unsigned)f2bf(v[1]) << 16);
                        o.y = (unsigned)f2bf(v[2]) | ((unsigned)f2bf(v[3]) << 16);
                        *(uint2*)&Cb[gm * 256 + w * 64 + nt * 16 + quad * 4] = o;
                    }
                }
            }
        } else {
            __syncthreads();   // all H reads complete before in-place overwrite
            #pragma unroll
            for (int j = 0; j < 4; j++) {
                int r = j * 16 + l16;
                #pragma unroll
                for (int nt = 0; nt < 4; nt++) {
                    f32x4 v = acc[j][nt] + bvv[nt];
                    int c = w * 8 + nt * 2 + (quad >> 1);
                    int cs = c ^ (r & 7);
                    uint2 o;
                    o.x = (unsigned)f2bf(v[0]) | ((unsigned)f2bf(v[1]) << 16);
                    o.y = (unsigned)f2bf(v[2]) | ((unsigned)f2bf(v[3]) << 16);
                    *(uint2*)&H[r * 256 + cs * 8 + (quad & 1) * 4] = o;
                }
            }
            __syncthreads();
        }
    }

    // ---- phase 3 (THREE only): out = H @ Wo + bo (N=128, fp32) ----
    if constexpr (THREE) {
        f32x4 acc3[4][2];
        #pragma unroll
        for (int j = 0; j < 4; j++)
            #pragma unroll
            for (int nt = 0; nt < 2; nt++) acc3[j][nt] = (f32x4)(0.f);
        #pragma unroll 4
        for (int ks = 0; ks < 8; ks++) {
            bf16x8 bw[2];
            #pragma unroll
            for (int nt = 0; nt < 2; nt++)
                bw[nt] = *(const bf16x8*)&W3t[(size_t)(w * 32 + nt * 16 + l16) * 256 + ks * 32 + quad * 8];
            #pragma unroll
            for (int j = 0; j < 4; j++) {
                int r = j * 16 + l16;
                int cs = (ks * 4 + quad) ^ (r & 7);
                bf16x8 af = *(const bf16x8*)&H[r * 256 + cs * 8];
                #pragma unroll
                for (int nt = 0; nt < 2; nt++)
                    acc3[j][nt] = __builtin_amdgcn_mfma_f32_16x16x32_bf16(bw[nt], af, acc3[j][nt], 0, 0, 0);
            }
        }
        f32x4 bv3[2];
        #pragma unroll
        for (int nt = 0; nt < 2; nt++)
            bv3[nt] = *(const f32x4*)&b3[w * 32 + nt * 16 + quad * 4];
        #pragma unroll
        for (int j = 0; j < 4; j++) {
            size_t gm = rowbase + j * 16 + l16;
            if (gm < (size_t)M) {
                #pragma unroll
                for (int nt = 0; nt < 2; nt++) {
                    f32x4 v = acc3[j][nt] + bv3[nt];
                    *(f32x4*)&Cf[gm * 128 + w * 32 + nt * 16 + quad * 4] = v;
                }
            }
        }
    }
}

// ---------------- launch ----------------

static inline size_t align256(size_t v) { return (v + 255) & ~(size_t)255; }

extern "C" void kernel_launch(void* const* d_in, const int* in_sizes, int n_in,
                              void* d_out, int out_size, void* d_ws, size_t ws_size,
                              hipStream_t stream) {
    const float* x        = (const float*)d_in[0];
    const int*   ei       = (const int*)d_in[1];
    const float* eps0     = (const float*)d_in[2];
    const float* W1_0     = (const float*)d_in[3];
    const float* b1_0     = (const float*)d_in[4];
    const float* W2_0     = (const float*)d_in[5];
    const float* b2_0     = (const float*)d_in[6];
    const float* eps1     = (const float*)d_in[7];
    const float* W1_1     = (const float*)d_in[8];
    const float* b1_1     = (const float*)d_in[9];
    const float* W2_1     = (const float*)d_in[10];
    const float* b2_1     = (const float*)d_in[11];
    const float* Wo       = (const float*)d_in[12];
    const float* bo       = (const float*)d_in[13];
    float* out            = (float*)d_out;

    const int* srcE = ei;
    const int* dstE = ei + NE;

    char* p = (char*)d_ws;
    size_t o = 0;
    int* cnt  = (int*)(p + o); o = align256(o + (size_t)NN * 4);
    int* srcs = (int*)(p + o); o = align256(o + (size_t)NN * MAXDEG * 4);
    unsigned short* xb   = (unsigned short*)(p + o); o = align256(o + (size_t)NN * DIN * 2);
    unsigned short* w10t = (unsigned short*)(p + o); o = align256(o + (size_t)DHID * DIN * 2);
    unsigned short* w20t = (unsigned short*)(p + o); o = align256(o + (size_t)DHID * DHID * 2);
    unsigned short* w11t = (unsigned short*)(p + o); o = align256(o + (size_t)DHID * DHID * 2);
    unsigned short* w21t = (unsigned short*)(p + o); o = align256(o + (size_t)DHID * DHID * 2);
    unsigned short* wot  = (unsigned short*)(p + o); o = align256(o + (size_t)DIN * DHID * 2);
    unsigned short* bufA = (unsigned short*)(p + o); o = align256(o + (size_t)NN * DHID * 2 + 65536);
    unsigned short* bufB = (unsigned short*)(p + o); o = align256(o + (size_t)NN * DHID * 2 + 65536);
    // +64KB pads: mlp_fused phase-1 last-block A over-read (47 rows x 512B max)

    prep_kernel<<<(NN * DIN / 4 + 255) / 256, 256, 0, stream>>>(
        x, xb, cnt, W1_0, W2_0, W1_1, W2_1, Wo, w10t, w20t, w11t, w21t, wot);
    bucket_kernel<<<(NE / 8 + 255) / 256, 256, 0, stream>>>(srcE, dstE, cnt, srcs, NE);

    int aggBlocks128 = ((NN + 3) / 4 + 3) / 4;   // 4 nodes/wave, 4 waves/block
    int aggBlocks256 = ((NN + 1) / 2 + 3) / 4;   // 2 nodes/wave
    int mlpBlocks = (NN + 63) / 64;              // 782

    // layer 0:  xb --agg--> bufA (D=128) --mlp0--> bufB (D=256)
    agg_bf16_kernel<DIN><<<aggBlocks128, 256, 0, stream>>>(xb, cnt, srcs, eps0, bufA, NN);
    mlp_fused<128, 0><<<mlpBlocks, 256, 0, stream>>>(
        bufA, w10t, b1_0, w20t, b2_0, nullptr, nullptr, bufB, nullptr, NN);

    // layer 1 + out:  bufB --agg--> bufA (D=256) --mlp1+o--> out (fp32)
    agg_bf16_kernel<DHID><<<aggBlocks256, 256, 0, stream>>>(bufB, cnt, srcs, eps1, bufA, NN);
    mlp_fused<256, 1><<<mlpBlocks, 256, 0, stream>>>(
        bufA, w11t, b1_1, w21t, b2_1, wot, bo, nullptr, out, NN);
}

// Round 5
// 336.180 us; speedup vs baseline: 1.0753x; 1.0753x over previous
//
#include <hip/hip_runtime.h>

#define NN 50000
#define NE 800000
#define DIN 128
#define DHID 256
#define MAXDEG 128   // Binomial(800k,1/50k): mean 16, sigma 4; 128 = 28 sigma

typedef __bf16 bf16x8 __attribute__((ext_vector_type(8)));
typedef float f32x4 __attribute__((ext_vector_type(4)));

static __device__ __forceinline__ unsigned short f2bf(float f) {
    unsigned u = __float_as_uint(f);
    unsigned r = 0x7fffu + ((u >> 16) & 1u);
    return (unsigned short)((u + r) >> 16);
}
static __device__ __forceinline__ float blo(unsigned u) { return __uint_as_float(u << 16); }
static __device__ __forceinline__ float bhi(unsigned u) { return __uint_as_float(u & 0xffff0000u); }

// ---------------- bucket build (fixed-stride buckets, x8 edge ILP) ----------------

__global__ void bucket_kernel(const int* __restrict__ src, const int* __restrict__ dst,
                              int* __restrict__ cnt, int* __restrict__ srcs, int E) {
    int i8 = (blockIdx.x * blockDim.x + threadIdx.x) * 8;
    if (i8 >= E) return;
    int4 da = *(const int4*)&dst[i8];
    int4 db = *(const int4*)&dst[i8 + 4];
    int4 sa = *(const int4*)&src[i8];
    int4 sb = *(const int4*)&src[i8 + 4];
    int t0 = atomicAdd(&cnt[da.x], 1);
    int t1 = atomicAdd(&cnt[da.y], 1);
    int t2 = atomicAdd(&cnt[da.z], 1);
    int t3 = atomicAdd(&cnt[da.w], 1);
    int t4 = atomicAdd(&cnt[db.x], 1);
    int t5 = atomicAdd(&cnt[db.y], 1);
    int t6 = atomicAdd(&cnt[db.z], 1);
    int t7 = atomicAdd(&cnt[db.w], 1);
    if (t0 < MAXDEG) srcs[(size_t)da.x * MAXDEG + t0] = sa.x;
    if (t1 < MAXDEG) srcs[(size_t)da.y * MAXDEG + t1] = sa.y;
    if (t2 < MAXDEG) srcs[(size_t)da.z * MAXDEG + t2] = sa.z;
    if (t3 < MAXDEG) srcs[(size_t)da.w * MAXDEG + t3] = sa.w;
    if (t4 < MAXDEG) srcs[(size_t)db.x * MAXDEG + t4] = sb.x;
    if (t5 < MAXDEG) srcs[(size_t)db.y * MAXDEG + t5] = sb.y;
    if (t6 < MAXDEG) srcs[(size_t)db.z * MAXDEG + t6] = sb.z;
    if (t7 < MAXDEG) srcs[(size_t)db.w * MAXDEG + t7] = sb.w;
}

// ---------------- prep: x fp32->bf16, zero cnt[], all 5 weights fp32->bf16 transposed ----------------

__global__ void prep_kernel(const float* __restrict__ x, unsigned short* __restrict__ xb,
                            int* __restrict__ cnt,
                            const float* __restrict__ W1_0, const float* __restrict__ W2_0,
                            const float* __restrict__ W1_1, const float* __restrict__ W2_1,
                            const float* __restrict__ Wo,
                            unsigned short* __restrict__ w10t, unsigned short* __restrict__ w20t,
                            unsigned short* __restrict__ w11t, unsigned short* __restrict__ w21t,
                            unsigned short* __restrict__ wot) {
    int i = blockIdx.x * blockDim.x + threadIdx.x;
    if (i < NN) cnt[i] = 0;
    if (i < 262144) {
        const float* W; unsigned short* Wt; int K, N, idx;
        if (i < 32768)        { W = W1_0; Wt = w10t; K = 128; N = 256; idx = i; }
        else if (i < 98304)   { W = W2_0; Wt = w20t; K = 256; N = 256; idx = i - 32768; }
        else if (i < 163840)  { W = W1_1; Wt = w11t; K = 256; N = 256; idx = i - 98304; }
        else if (i < 229376)  { W = W2_1; Wt = w21t; K = 256; N = 256; idx = i - 163840; }
        else                  { W = Wo;   Wt = wot;  K = 256; N = 128; idx = i - 229376; }
        int k = idx / N;
        int n = idx - k * N;
        Wt[(size_t)n * K + k] = f2bf(W[idx]);
    }
    if (i * 4 < NN * DIN) {
        float4 v = *(const float4*)(x + (size_t)i * 4);
        ushort4 o;
        o.x = f2bf(v.x); o.y = f2bf(v.y); o.z = f2bf(v.z); o.w = f2bf(v.w);
        *(ushort4*)(xb + (size_t)i * 4) = o;
    }
}

// ---------------- fused GIN layer v6: gather-agg (phase 0, LDS) + MLP ----------------
// R4 post-mortem: afr[][] A-prefetch = 128 VGPR -> scratch spill (WRITE 25->125MB).
// R1/R3/R4 all failed to fix mlp's latency-bound phase-1 A stream from HBM. v6 removes
// it structurally: each block gather-aggregates its own 64 node rows (exact agg loop,
// bit-identical fp32 order) into LDS as phase 0, then MFMAs from LDS. Deletes per
// layer: bufA HBM write (25.6MB) + mlp A HBM read (13.9MB) + the grid-wide
// agg->mlp barrier (gather of block k overlaps MFMA of block k-1; 3-4 blocks/CU
// co-resident) + 2 dispatches. A-tile is unioned with H (A fully consumed by phase-1
// K-loop; one extra barrier) so LDS stays 32KB. A uses the H-style XOR chunk swizzle
// (cs = chunk ^ (row&7), 16B chunks) on both write and read sides.
// C = [relu(A@W1+b1)@W2+b2] (@Wo+bo if THREE). Weights pre-transposed [N][K] bf16,
// L2-resident. ks-OUTER W streaming, acc[4][4] across full K (verified R2 config).

template <int K1, int THREE>
__global__ __launch_bounds__(256) void mlp_fused(
        const unsigned short* __restrict__ X,       // gather table [*, K1] bf16
        const int* __restrict__ cnt, const int* __restrict__ srcs,
        const float* __restrict__ eps_p,
        const unsigned short* __restrict__ W1t, const float* __restrict__ b1,
        const unsigned short* __restrict__ W2t, const float* __restrict__ b2,
        const unsigned short* __restrict__ W3t, const float* __restrict__ b3,
        unsigned short* __restrict__ Cb, float* __restrict__ Cf, int M) {
    constexpr int NKS1 = K1 / 32;
    constexpr int G = (K1 == 128) ? 4 : 2;   // nodes gathered per wave-pass
    constexpr int L = 64 / G;                // lanes per node
    constexpr int RQ = K1 / 8;               // uint4 per row
    __shared__ __align__(16) unsigned short H[64 * 256];   // 32KB union: phase-0 A / H

    const int lane = threadIdx.x & 63;
    const int w = threadIdx.x >> 6;      // n-slice / gather row-slice
    const int quad = lane >> 4;
    const int l16 = lane & 15;
    const size_t rowbase = (size_t)blockIdx.x * 64;

    // ---- phase 0: gather-aggregate 64 node rows into LDS (A-layout, swizzled) ----
    {
        const int group = lane / L;
        const int li = lane % L;
        const uint4* xp = (const uint4*)X;
        const float e = 1.0f + eps_p[0];
        for (int p = 0; p < 16 / G; p++) {
            const int r = w * 16 + p * G + group;
            const size_t node = rowbase + r;
            if (node < (size_t)M) {
                int deg = cnt[node]; if (deg > MAXDEG) deg = MAXDEG;
                const int* sp = srcs + (size_t)node * MAXDEG;
                float a[8], b[8];
                #pragma unroll
                for (int j = 0; j < 8; j++) { a[j] = 0.f; b[j] = 0.f; }
                int i = 0;
                for (; i + 8 <= deg; i += 8) {
                    int4 s0 = *(const int4*)&sp[i];
                    int4 s1 = *(const int4*)&sp[i + 4];
                    uint4 v0 = xp[(size_t)s0.x * RQ + li];
                    uint4 v1 = xp[(size_t)s0.y * RQ + li];
                    uint4 v2 = xp[(size_t)s0.z * RQ + li];
                    uint4 v3 = xp[(size_t)s0.w * RQ + li];
                    uint4 v4 = xp[(size_t)s1.x * RQ + li];
                    uint4 v5 = xp[(size_t)s1.y * RQ + li];
                    uint4 v6 = xp[(size_t)s1.z * RQ + li];
                    uint4 v7 = xp[(size_t)s1.w * RQ + li];
                    a[0] += blo(v0.x); a[1] += bhi(v0.x); a[2] += blo(v0.y); a[3] += bhi(v0.y);
                    a[4] += blo(v0.z); a[5] += bhi(v0.z); a[6] += blo(v0.w); a[7] += bhi(v0.w);
                    b[0] += blo(v1.x); b[1] += bhi(v1.x); b[2] += blo(v1.y); b[3] += bhi(v1.y);
                    b[4] += blo(v1.z); b[5] += bhi(v1.z); b[6] += blo(v1.w); b[7] += bhi(v1.w);
                    a[0] += blo(v2.x); a[1] += bhi(v2.x); a[2] += blo(v2.y); a[3] += bhi(v2.y);
                    a[4] += blo(v2.z); a[5] += bhi(v2.z); a[6] += blo(v2.w); a[7] += bhi(v2.w);
                    b[0] += blo(v3.x); b[1] += bhi(v3.x); b[2] += blo(v3.y); b[3] += bhi(v3.y);
                    b[4] += blo(v3.z); b[5] += bhi(v3.z); b[6] += blo(v3.w); b[7] += bhi(v3.w);
                    a[0] += blo(v4.x); a[1] += bhi(v4.x); a[2] += blo(v4.y); a[3] += bhi(v4.y);
                    a[4] += blo(v4.z); a[5] += bhi(v4.z); a[6] += blo(v4.w); a[7] += bhi(v4.w);
                    b[0] += blo(v5.x); b[1] += bhi(v5.x); b[2] += blo(v5.y); b[3] += bhi(v5.y);
                    b[4] += blo(v5.z); b[5] += bhi(v5.z); b[6] += blo(v5.w); b[7] += bhi(v5.w);
                    a[0] += blo(v6.x); a[1] += bhi(v6.x); a[2] += blo(v6.y); a[3] += bhi(v6.y);
                    a[4] += blo(v6.z); a[5] += bhi(v6.z); a[6] += blo(v6.w); a[7] += bhi(v6.w);
                    b[0] += blo(v7.x); b[1] += bhi(v7.x); b[2] += blo(v7.y); b[3] += bhi(v7.y);
                    b[4] += blo(v7.z); b[5] += bhi(v7.z); b[6] += blo(v7.w); b[7] += bhi(v7.w);
                }
                for (; i + 4 <= deg; i += 4) {
                    int4 s = *(const int4*)&sp[i];
                    uint4 v0 = xp[(size_t)s.x * RQ + li];
                    uint4 v1 = xp[(size_t)s.y * RQ + li];
                    uint4 v2 = xp[(size_t)s.z * RQ + li];
                    uint4 v3 = xp[(size_t)s.w * RQ + li];
                    a[0] += blo(v0.x); a[1] += bhi(v0.x); a[2] += blo(v0.y); a[3] += bhi(v0.y);
                    a[4] += blo(v0.z); a[5] += bhi(v0.z); a[6] += blo(v0.w); a[7] += bhi(v0.w);
                    b[0] += blo(v1.x); b[1] += bhi(v1.x); b[2] += blo(v1.y); b[3] += bhi(v1.y);
                    b[4] += blo(v1.z); b[5] += bhi(v1.z); b[6] += blo(v1.w); b[7] += bhi(v1.w);
                    a[0] += blo(v2.x); a[1] += bhi(v2.x); a[2] += blo(v2.y); a[3] += bhi(v2.y);
                    a[4] += blo(v2.z); a[5] += bhi(v2.z); a[6] += blo(v2.w); a[7] += bhi(v2.w);
                    b[0] += blo(v3.x); b[1] += bhi(v3.x); b[2] += blo(v3.y); b[3] += bhi(v3.y);
                    b[4] += blo(v3.z); b[5] += bhi(v3.z); b[6] += blo(v3.w); b[7] += bhi(v3.w);
                }
                for (; i < deg; i++) {
                    uint4 v = xp[(size_t)sp[i] * RQ + li];
                    a[0] += blo(v.x); a[1] += bhi(v.x); a[2] += blo(v.y); a[3] += bhi(v.y);
                    a[4] += blo(v.z); a[5] += bhi(v.z); a[6] += blo(v.w); a[7] += bhi(v.w);
                }
                uint4 xv = xp[(size_t)node * RQ + li];
                a[0] += b[0] + e * blo(xv.x); a[1] += b[1] + e * bhi(xv.x);
                a[2] += b[2] + e * blo(xv.y); a[3] += b[3] + e * bhi(xv.y);
                a[4] += b[4] + e * blo(xv.z); a[5] += b[5] + e * bhi(xv.z);
                a[6] += b[6] + e * blo(xv.w); a[7] += b[7] + e * bhi(xv.w);
                uint4 o;
                o.x = (unsigned)f2bf(a[0]) | ((unsigned)f2bf(a[1]) << 16);
                o.y = (unsigned)f2bf(a[2]) | ((unsigned)f2bf(a[3]) << 16);
                o.z = (unsigned)f2bf(a[4]) | ((unsigned)f2bf(a[5]) << 16);
                o.w = (unsigned)f2bf(a[6]) | ((unsigned)f2bf(a[7]) << 16);
                const int cs = li ^ (r & 7);   // 16B-chunk XOR swizzle (A-layout)
                *(uint4*)&H[r * K1 + cs * 8] = o;
            }
        }
    }
    __syncthreads();

    f32x4 acc[4][4];

    // ---- phase 1: acc = A(LDS) @ W1 (stream W1) ----
    #pragma unroll
    for (int j = 0; j < 4; j++)
        #pragma unroll
        for (int nt = 0; nt < 4; nt++) acc[j][nt] = (f32x4)(0.f);
    #pragma unroll 2
    for (int ks = 0; ks < NKS1; ks++) {
        bf16x8 bw[4];
        #pragma unroll
        for (int nt = 0; nt < 4; nt++)
            bw[nt] = *(const bf16x8*)&W1t[(size_t)(w * 64 + nt * 16 + l16) * K1 + ks * 32 + quad * 8];
        #pragma unroll
        for (int j = 0; j < 4; j++) {
            int r = j * 16 + l16;
            int cs = (ks * 4 + quad) ^ (r & 7);
            bf16x8 af = *(const bf16x8*)&H[r * K1 + cs * 8];
            #pragma unroll
            for (int nt = 0; nt < 4; nt++)
                acc[j][nt] = __builtin_amdgcn_mfma_f32_16x16x32_bf16(bw[nt], af, acc[j][nt], 0, 0, 0);
        }
    }
    __syncthreads();   // A fully consumed by all waves before H overwrites it
    {   // epilogue 1: bias + relu -> H (swizzled)
        f32x4 bvv[4];
        #pragma unroll
        for (int nt = 0; nt < 4; nt++)
            bvv[nt] = *(const f32x4*)&b1[w * 64 + nt * 16 + quad * 4];
        #pragma unroll
        for (int j = 0; j < 4; j++) {
            int r = j * 16 + l16;
            #pragma unroll
            for (int nt = 0; nt < 4; nt++) {
                f32x4 v = acc[j][nt] + bvv[nt];
                v[0] = fmaxf(v[0], 0.f); v[1] = fmaxf(v[1], 0.f);
                v[2] = fmaxf(v[2], 0.f); v[3] = fmaxf(v[3], 0.f);
                int c = w * 8 + nt * 2 + (quad >> 1);
                int cs = c ^ (r & 7);
                uint2 o;
                o.x = (unsigned)f2bf(v[0]) | ((unsigned)f2bf(v[1]) << 16);
                o.y = (unsigned)f2bf(v[2]) | ((unsigned)f2bf(v[3]) << 16);
                *(uint2*)&H[r * 256 + cs * 8 + (quad & 1) * 4] = o;
            }
        }
    }
    __syncthreads();

    // ---- phase 2: acc = H @ W2 (stream W2, K=256) ----
    #pragma unroll
    for (int j = 0; j < 4; j++)
        #pragma unroll
        for (int nt = 0; nt < 4; nt++) acc[j][nt] = (f32x4)(0.f);
    #pragma unroll 2
    for (int ks = 0; ks < 8; ks++) {
        bf16x8 bw[4];
        #pragma unroll
        for (int nt = 0; nt < 4; nt++)
            bw[nt] = *(const bf16x8*)&W2t[(size_t)(w * 64 + nt * 16 + l16) * 256 + ks * 32 + quad * 8];
        #pragma unroll
        for (int j = 0; j < 4; j++) {
            int r = j * 16 + l16;
            int cs = (ks * 4 + quad) ^ (r & 7);
            bf16x8 af = *(const bf16x8*)&H[r * 256 + cs * 8];
            #pragma unroll
            for (int nt = 0; nt < 4; nt++)
                acc[j][nt] = __builtin_amdgcn_mfma_f32_16x16x32_bf16(bw[nt], af, acc[j][nt], 0, 0, 0);
        }
    }
    {
        f32x4 bvv[4];
        #pragma unroll
        for (int nt = 0; nt < 4; nt++)
            bvv[nt] = *(const f32x4*)&b2[w * 64 + nt * 16 + quad * 4];
        if constexpr (!THREE) {
            #pragma unroll
            for (int j = 0; j < 4; j++) {
                size_t gm = rowbase + j * 16 + l16;
                if (gm < (size_t)M) {
                    #pragma unroll
                    for (int nt = 0; nt < 4; nt++) {
                        f32x4 v = acc[j][nt] + bvv[nt];
                        uint2 o;
                        o.x = (unsigned)f2bf(v[0]) | ((unsigned)f2bf(v[1]) << 16);
                        o.y = (unsigned)f2bf(v[2]) | ((unsigned)f2bf(v[3]) << 16);
                        *(uint2*)&Cb[gm * 256 + w * 64 + nt * 16 + quad * 4] = o;
                    }
                }
            }
        } else {
            __syncthreads();   // all H reads complete before in-place overwrite
            #pragma unroll
            for (int j = 0; j < 4; j++) {
                int r = j * 16 + l16;
                #pragma unroll
                for (int nt = 0; nt < 4; nt++) {
                    f32x4 v = acc[j][nt] + bvv[nt];
                    int c = w * 8 + nt * 2 + (quad >> 1);
                    int cs = c ^ (r & 7);
                    uint2 o;
                    o.x = (unsigned)f2bf(v[0]) | ((unsigned)f2bf(v[1]) << 16);
                    o.y = (unsigned)f2bf(v[2]) | ((unsigned)f2bf(v[3]) << 16);
                    *(uint2*)&H[r * 256 + cs * 8 + (quad & 1) * 4] = o;
                }
            }
            __syncthreads();
        }
    }

    // ---- phase 3 (THREE only): out = H @ Wo + bo (N=128, fp32) ----
    if constexpr (THREE) {
        f32x4 acc3[4][2];
        #pragma unroll
        for (int j = 0; j < 4; j++)
            #pragma unroll
            for (int nt = 0; nt < 2; nt++) acc3[j][nt] = (f32x4)(0.f);
        #pragma unroll 2
        for (int ks = 0; ks < 8; ks++) {
            bf16x8 bw[2];
            #pragma unroll
            for (int nt = 0; nt < 2; nt++)
                bw[nt] = *(const bf16x8*)&W3t[(size_t)(w * 32 + nt * 16 + l16) * 256 + ks * 32 + quad * 8];
            #pragma unroll
            for (int j = 0; j < 4; j++) {
                int r = j * 16 + l16;
                int cs = (ks * 4 + quad) ^ (r & 7);
                bf16x8 af = *(const bf16x8*)&H[r * 256 + cs * 8];
                #pragma unroll
                for (int nt = 0; nt < 2; nt++)
                    acc3[j][nt] = __builtin_amdgcn_mfma_f32_16x16x32_bf16(bw[nt], af, acc3[j][nt], 0, 0, 0);
            }
        }
        f32x4 bv3[2];
        #pragma unroll
        for (int nt = 0; nt < 2; nt++)
            bv3[nt] = *(const f32x4*)&b3[w * 32 + nt * 16 + quad * 4];
        #pragma unroll
        for (int j = 0; j < 4; j++) {
            size_t gm = rowbase + j * 16 + l16;
            if (gm < (size_t)M) {
                #pragma unroll
                for (int nt = 0; nt < 2; nt++) {
                    f32x4 v = acc3[j][nt] + bv3[nt];
                    *(f32x4*)&Cf[gm * 128 + w * 32 + nt * 16 + quad * 4] = v;
                }
            }
        }
    }
}

// ---------------- launch ----------------

static inline size_t align256(size_t v) { return (v + 255) & ~(size_t)255; }

extern "C" void kernel_launch(void* const* d_in, const int* in_sizes, int n_in,
                              void* d_out, int out_size, void* d_ws, size_t ws_size,
                              hipStream_t stream) {
    const float* x        = (const float*)d_in[0];
    const int*   ei       = (const int*)d_in[1];
    const float* eps0     = (const float*)d_in[2];
    const float* W1_0     = (const float*)d_in[3];
    const float* b1_0     = (const float*)d_in[4];
    const float* W2_0     = (const float*)d_in[5];
    const float* b2_0     = (const float*)d_in[6];
    const float* eps1     = (const float*)d_in[7];
    const float* W1_1     = (const float*)d_in[8];
    const float* b1_1     = (const float*)d_in[9];
    const float* W2_1     = (const float*)d_in[10];
    const float* b2_1     = (const float*)d_in[11];
    const float* Wo       = (const float*)d_in[12];
    const float* bo       = (const float*)d_in[13];
    float* out            = (float*)d_out;

    const int* srcE = ei;
    const int* dstE = ei + NE;

    char* p = (char*)d_ws;
    size_t o = 0;
    int* cnt  = (int*)(p + o); o = align256(o + (size_t)NN * 4);
    int* srcs = (int*)(p + o); o = align256(o + (size_t)NN * MAXDEG * 4);
    unsigned short* xb   = (unsigned short*)(p + o); o = align256(o + (size_t)NN * DIN * 2);
    unsigned short* w10t = (unsigned short*)(p + o); o = align256(o + (size_t)DHID * DIN * 2);
    unsigned short* w20t = (unsigned short*)(p + o); o = align256(o + (size_t)DHID * DHID * 2);
    unsigned short* w11t = (unsigned short*)(p + o); o = align256(o + (size_t)DHID * DHID * 2);
    unsigned short* w21t = (unsigned short*)(p + o); o = align256(o + (size_t)DHID * DHID * 2);
    unsigned short* wot  = (unsigned short*)(p + o); o = align256(o + (size_t)DIN * DHID * 2);
    unsigned short* bufB = (unsigned short*)(p + o); o = align256(o + (size_t)NN * DHID * 2);

    prep_kernel<<<(NN * DIN / 4 + 255) / 256, 256, 0, stream>>>(
        x, xb, cnt, W1_0, W2_0, W1_1, W2_1, Wo, w10t, w20t, w11t, w21t, wot);
    bucket_kernel<<<(NE / 8 + 255) / 256, 256, 0, stream>>>(srcE, dstE, cnt, srcs, NE);

    int mlpBlocks = (NN + 63) / 64;              // 782

    // layer 0:  xb --[gather+agg+mlp0]--> bufB (bf16, D=256)
    mlp_fused<128, 0><<<mlpBlocks, 256, 0, stream>>>(
        xb, cnt, srcs, eps0, w10t, b1_0, w20t, b2_0, nullptr, nullptr, bufB, nullptr, NN);

    // layer 1 + out:  bufB --[gather+agg+mlp1+o]--> out (fp32, D=128)
    mlp_fused<256, 1><<<mlpBlocks, 256, 0, stream>>>(
        bufB, cnt, srcs, eps1, w11t, b1_1, w21t, b2_1, wot, bo, nullptr, out, NN);
}

// Round 6
// 306.276 us; speedup vs baseline: 1.1803x; 1.0976x over previous
//
#include <hip/hip_runtime.h>

#define NN 50000
#define NE 800000
#define DIN 128
#define DHID 256
#define MAXDEG 128   // Binomial(800k,1/50k): mean 16, sigma 4; 128 = 28 sigma

typedef __bf16 bf16x8 __attribute__((ext_vector_type(8)));
typedef float f32x4 __attribute__((ext_vector_type(4)));

static __device__ __forceinline__ unsigned short f2bf(float f) {
    unsigned u = __float_as_uint(f);
    unsigned r = 0x7fffu + ((u >> 16) & 1u);
    return (unsigned short)((u + r) >> 16);
}
static __device__ __forceinline__ float blo(unsigned u) { return __uint_as_float(u << 16); }
static __device__ __forceinline__ float bhi(unsigned u) { return __uint_as_float(u & 0xffff0000u); }

// ---------------- bucket build (fixed-stride buckets, x8 edge ILP) ----------------

__global__ void bucket_kernel(const int* __restrict__ src, const int* __restrict__ dst,
                              int* __restrict__ cnt, int* __restrict__ srcs, int E) {
    int i8 = (blockIdx.x * blockDim.x + threadIdx.x) * 8;
    if (i8 >= E) return;
    int4 da = *(const int4*)&dst[i8];
    int4 db = *(const int4*)&dst[i8 + 4];
    int4 sa = *(const int4*)&src[i8];
    int4 sb = *(const int4*)&src[i8 + 4];
    int t0 = atomicAdd(&cnt[da.x], 1);
    int t1 = atomicAdd(&cnt[da.y], 1);
    int t2 = atomicAdd(&cnt[da.z], 1);
    int t3 = atomicAdd(&cnt[da.w], 1);
    int t4 = atomicAdd(&cnt[db.x], 1);
    int t5 = atomicAdd(&cnt[db.y], 1);
    int t6 = atomicAdd(&cnt[db.z], 1);
    int t7 = atomicAdd(&cnt[db.w], 1);
    if (t0 < MAXDEG) srcs[(size_t)da.x * MAXDEG + t0] = sa.x;
    if (t1 < MAXDEG) srcs[(size_t)da.y * MAXDEG + t1] = sa.y;
    if (t2 < MAXDEG) srcs[(size_t)da.z * MAXDEG + t2] = sa.z;
    if (t3 < MAXDEG) srcs[(size_t)da.w * MAXDEG + t3] = sa.w;
    if (t4 < MAXDEG) srcs[(size_t)db.x * MAXDEG + t4] = sb.x;
    if (t5 < MAXDEG) srcs[(size_t)db.y * MAXDEG + t5] = sb.y;
    if (t6 < MAXDEG) srcs[(size_t)db.z * MAXDEG + t6] = sb.z;
    if (t7 < MAXDEG) srcs[(size_t)db.w * MAXDEG + t7] = sb.w;
}

// ---------------- prep: x fp32->bf16, zero cnt[], all 5 weights fp32->bf16 transposed ----------------

__global__ void prep_kernel(const float* __restrict__ x, unsigned short* __restrict__ xb,
                            int* __restrict__ cnt,
                            const float* __restrict__ W1_0, const float* __restrict__ W2_0,
                            const float* __restrict__ W1_1, const float* __restrict__ W2_1,
                            const float* __restrict__ Wo,
                            unsigned short* __restrict__ w10t, unsigned short* __restrict__ w20t,
                            unsigned short* __restrict__ w11t, unsigned short* __restrict__ w21t,
                            unsigned short* __restrict__ wot) {
    int i = blockIdx.x * blockDim.x + threadIdx.x;
    if (i < NN) cnt[i] = 0;
    if (i < 262144) {
        const float* W; unsigned short* Wt; int K, N, idx;
        if (i < 32768)        { W = W1_0; Wt = w10t; K = 128; N = 256; idx = i; }
        else if (i < 98304)   { W = W2_0; Wt = w20t; K = 256; N = 256; idx = i - 32768; }
        else if (i < 163840)  { W = W1_1; Wt = w11t; K = 256; N = 256; idx = i - 98304; }
        else if (i < 229376)  { W = W2_1; Wt = w21t; K = 256; N = 256; idx = i - 163840; }
        else                  { W = Wo;   Wt = wot;  K = 256; N = 128; idx = i - 229376; }
        int k = idx / N;
        int n = idx - k * N;
        Wt[(size_t)n * K + k] = f2bf(W[idx]);
    }
    if (i * 4 < NN * DIN) {
        float4 v = *(const float4*)(x + (size_t)i * 4);
        ushort4 o;
        o.x = f2bf(v.x); o.y = f2bf(v.y); o.z = f2bf(v.z); o.w = f2bf(v.w);
        *(ushort4*)(xb + (size_t)i * 4) = o;
    }
}

// ---------------- fused GIN layer v7: 8-wave blocks (gather parallelism + N-split MLP) ----------------
// R5 post-mortem: fusion ~neutral. FETCH 187MB = 7.3x table = 8-XCD L2 duplication
// floor (gather TRAFFIC is irreducible); but fused gather CONCURRENCY was poor:
// occupancy 16.7% (~1.3 blocks/CU) and 8 serial row-passes per wave. v7: 512 threads /
// 8 waves per block. Gather: each wave owns 8 rows (half the serial passes, 2x in-
// flight loads/CU). MLP: R3-verified 8-wave N-split layout (nt=2; same per-block
// W-instruction count, blocks stay 782 -> R1 constraint respected). Phase-0 inner loop
// verbatim from R5 (bit-identical accumulation); MLP phases verbatim from R3.
// A-tile unioned with H in 32KB LDS; A consumed by phase-1 K-loop, extra barrier,
// then H overwrites. XOR 16B-chunk swizzle on A (cs = li ^ (r&7)) and H.

template <int K1, int THREE>
__global__ __launch_bounds__(512) void mlp_fused(
        const unsigned short* __restrict__ X,       // gather table [*, K1] bf16
        const int* __restrict__ cnt, const int* __restrict__ srcs,
        const float* __restrict__ eps_p,
        const unsigned short* __restrict__ W1t, const float* __restrict__ b1,
        const unsigned short* __restrict__ W2t, const float* __restrict__ b2,
        const unsigned short* __restrict__ W3t, const float* __restrict__ b3,
        unsigned short* __restrict__ Cb, float* __restrict__ Cf, int M) {
    constexpr int NKS1 = K1 / 32;
    constexpr int G = (K1 == 128) ? 4 : 2;   // nodes gathered per wave-pass
    constexpr int L = 64 / G;                // lanes per node
    constexpr int RQ = K1 / 8;               // uint4 per row
    __shared__ __align__(16) unsigned short H[64 * 256];   // 32KB union: phase-0 A / H

    const int lane = threadIdx.x & 63;
    const int w = threadIdx.x >> 6;      // wave id 0..7: n-slice / gather row-slice
    const int quad = lane >> 4;
    const int l16 = lane & 15;
    const size_t rowbase = (size_t)blockIdx.x * 64;

    // ---- phase 0: gather-aggregate 64 node rows into LDS (A-layout, swizzled) ----
    {
        const int group = lane / L;
        const int li = lane % L;
        const uint4* xp = (const uint4*)X;
        const float e = 1.0f + eps_p[0];
        #pragma unroll
        for (int p = 0; p < 8 / G; p++) {
            const int r = w * 8 + p * G + group;
            const size_t node = rowbase + r;
            if (node < (size_t)M) {
                int deg = cnt[node]; if (deg > MAXDEG) deg = MAXDEG;
                const int* sp = srcs + (size_t)node * MAXDEG;
                float a[8], b[8];
                #pragma unroll
                for (int j = 0; j < 8; j++) { a[j] = 0.f; b[j] = 0.f; }
                int i = 0;
                for (; i + 8 <= deg; i += 8) {
                    int4 s0 = *(const int4*)&sp[i];
                    int4 s1 = *(const int4*)&sp[i + 4];
                    uint4 v0 = xp[(size_t)s0.x * RQ + li];
                    uint4 v1 = xp[(size_t)s0.y * RQ + li];
                    uint4 v2 = xp[(size_t)s0.z * RQ + li];
                    uint4 v3 = xp[(size_t)s0.w * RQ + li];
                    uint4 v4 = xp[(size_t)s1.x * RQ + li];
                    uint4 v5 = xp[(size_t)s1.y * RQ + li];
                    uint4 v6 = xp[(size_t)s1.z * RQ + li];
                    uint4 v7 = xp[(size_t)s1.w * RQ + li];
                    a[0] += blo(v0.x); a[1] += bhi(v0.x); a[2] += blo(v0.y); a[3] += bhi(v0.y);
                    a[4] += blo(v0.z); a[5] += bhi(v0.z); a[6] += blo(v0.w); a[7] += bhi(v0.w);
                    b[0] += blo(v1.x); b[1] += bhi(v1.x); b[2] += blo(v1.y); b[3] += bhi(v1.y);
                    b[4] += blo(v1.z); b[5] += bhi(v1.z); b[6] += blo(v1.w); b[7] += bhi(v1.w);
                    a[0] += blo(v2.x); a[1] += bhi(v2.x); a[2] += blo(v2.y); a[3] += bhi(v2.y);
                    a[4] += blo(v2.z); a[5] += bhi(v2.z); a[6] += blo(v2.w); a[7] += bhi(v2.w);
                    b[0] += blo(v3.x); b[1] += bhi(v3.x); b[2] += blo(v3.y); b[3] += bhi(v3.y);
                    b[4] += blo(v3.z); b[5] += bhi(v3.z); b[6] += blo(v3.w); b[7] += bhi(v3.w);
                    a[0] += blo(v4.x); a[1] += bhi(v4.x); a[2] += blo(v4.y); a[3] += bhi(v4.y);
                    a[4] += blo(v4.z); a[5] += bhi(v4.z); a[6] += blo(v4.w); a[7] += bhi(v4.w);
                    b[0] += blo(v5.x); b[1] += bhi(v5.x); b[2] += blo(v5.y); b[3] += bhi(v5.y);
                    b[4] += blo(v5.z); b[5] += bhi(v5.z); b[6] += blo(v5.w); b[7] += bhi(v5.w);
                    a[0] += blo(v6.x); a[1] += bhi(v6.x); a[2] += blo(v6.y); a[3] += bhi(v6.y);
                    a[4] += blo(v6.z); a[5] += bhi(v6.z); a[6] += blo(v6.w); a[7] += bhi(v6.w);
                    b[0] += blo(v7.x); b[1] += bhi(v7.x); b[2] += blo(v7.y); b[3] += bhi(v7.y);
                    b[4] += blo(v7.z); b[5] += bhi(v7.z); b[6] += blo(v7.w); b[7] += bhi(v7.w);
                }
                for (; i + 4 <= deg; i += 4) {
                    int4 s = *(const int4*)&sp[i];
                    uint4 v0 = xp[(size_t)s.x * RQ + li];
                    uint4 v1 = xp[(size_t)s.y * RQ + li];
                    uint4 v2 = xp[(size_t)s.z * RQ + li];
                    uint4 v3 = xp[(size_t)s.w * RQ + li];
                    a[0] += blo(v0.x); a[1] += bhi(v0.x); a[2] += blo(v0.y); a[3] += bhi(v0.y);
                    a[4] += blo(v0.z); a[5] += bhi(v0.z); a[6] += blo(v0.w); a[7] += bhi(v0.w);
                    b[0] += blo(v1.x); b[1] += bhi(v1.x); b[2] += blo(v1.y); b[3] += bhi(v1.y);
                    b[4] += blo(v1.z); b[5] += bhi(v1.z); b[6] += blo(v1.w); b[7] += bhi(v1.w);
                    a[0] += blo(v2.x); a[1] += bhi(v2.x); a[2] += blo(v2.y); a[3] += bhi(v2.y);
                    a[4] += blo(v2.z); a[5] += bhi(v2.z); a[6] += blo(v2.w); a[7] += bhi(v2.w);
                    b[0] += blo(v3.x); b[1] += bhi(v3.x); b[2] += blo(v3.y); b[3] += bhi(v3.y);
                    b[4] += blo(v3.z); b[5] += bhi(v3.z); b[6] += blo(v3.w); b[7] += bhi(v3.w);
                }
                for (; i < deg; i++) {
                    uint4 v = xp[(size_t)sp[i] * RQ + li];
                    a[0] += blo(v.x); a[1] += bhi(v.x); a[2] += blo(v.y); a[3] += bhi(v.y);
                    a[4] += blo(v.z); a[5] += bhi(v.z); a[6] += blo(v.w); a[7] += bhi(v.w);
                }
                uint4 xv = xp[(size_t)node * RQ + li];
                a[0] += b[0] + e * blo(xv.x); a[1] += b[1] + e * bhi(xv.x);
                a[2] += b[2] + e * blo(xv.y); a[3] += b[3] + e * bhi(xv.y);
                a[4] += b[4] + e * blo(xv.z); a[5] += b[5] + e * bhi(xv.z);
                a[6] += b[6] + e * blo(xv.w); a[7] += b[7] + e * bhi(xv.w);
                uint4 o;
                o.x = (unsigned)f2bf(a[0]) | ((unsigned)f2bf(a[1]) << 16);
                o.y = (unsigned)f2bf(a[2]) | ((unsigned)f2bf(a[3]) << 16);
                o.z = (unsigned)f2bf(a[4]) | ((unsigned)f2bf(a[5]) << 16);
                o.w = (unsigned)f2bf(a[6]) | ((unsigned)f2bf(a[7]) << 16);
                const int cs = li ^ (r & 7);   // 16B-chunk XOR swizzle (A-layout)
                *(uint4*)&H[r * K1 + cs * 8] = o;
            }
        }
    }
    __syncthreads();

    f32x4 acc[4][2];

    // ---- phase 1: acc = A(LDS) @ W1 (stream W1, 8-wave N-split) ----
    #pragma unroll
    for (int j = 0; j < 4; j++)
        #pragma unroll
        for (int nt = 0; nt < 2; nt++) acc[j][nt] = (f32x4)(0.f);
    #pragma unroll 2
    for (int ks = 0; ks < NKS1; ks++) {
        bf16x8 bw[2];
        #pragma unroll
        for (int nt = 0; nt < 2; nt++)
            bw[nt] = *(const bf16x8*)&W1t[(size_t)(w * 32 + nt * 16 + l16) * K1 + ks * 32 + quad * 8];
        #pragma unroll
        for (int j = 0; j < 4; j++) {
            int r = j * 16 + l16;
            int cs = (ks * 4 + quad) ^ (r & 7);
            bf16x8 af = *(const bf16x8*)&H[r * K1 + cs * 8];
            #pragma unroll
            for (int nt = 0; nt < 2; nt++)
                acc[j][nt] = __builtin_amdgcn_mfma_f32_16x16x32_bf16(bw[nt], af, acc[j][nt], 0, 0, 0);
        }
    }
    __syncthreads();   // A fully consumed by all waves before H overwrites it
    {   // epilogue 1: bias + relu -> H (swizzled)
        f32x4 bvv[2];
        #pragma unroll
        for (int nt = 0; nt < 2; nt++)
            bvv[nt] = *(const f32x4*)&b1[w * 32 + nt * 16 + quad * 4];
        #pragma unroll
        for (int j = 0; j < 4; j++) {
            int r = j * 16 + l16;
            #pragma unroll
            for (int nt = 0; nt < 2; nt++) {
                f32x4 v = acc[j][nt] + bvv[nt];
                v[0] = fmaxf(v[0], 0.f); v[1] = fmaxf(v[1], 0.f);
                v[2] = fmaxf(v[2], 0.f); v[3] = fmaxf(v[3], 0.f);
                int c = w * 4 + nt * 2 + (quad >> 1);
                int cs = c ^ (r & 7);
                uint2 o;
                o.x = (unsigned)f2bf(v[0]) | ((unsigned)f2bf(v[1]) << 16);
                o.y = (unsigned)f2bf(v[2]) | ((unsigned)f2bf(v[3]) << 16);
                *(uint2*)&H[r * 256 + cs * 8 + (quad & 1) * 4] = o;
            }
        }
    }
    __syncthreads();

    // ---- phase 2: acc = H @ W2 (stream W2, K=256) ----
    #pragma unroll
    for (int j = 0; j < 4; j++)
        #pragma unroll
        for (int nt = 0; nt < 2; nt++) acc[j][nt] = (f32x4)(0.f);
    #pragma unroll 2
    for (int ks = 0; ks < 8; ks++) {
        bf16x8 bw[2];
        #pragma unroll
        for (int nt = 0; nt < 2; nt++)
            bw[nt] = *(const bf16x8*)&W2t[(size_t)(w * 32 + nt * 16 + l16) * 256 + ks * 32 + quad * 8];
        #pragma unroll
        for (int j = 0; j < 4; j++) {
            int r = j * 16 + l16;
            int cs = (ks * 4 + quad) ^ (r & 7);
            bf16x8 af = *(const bf16x8*)&H[r * 256 + cs * 8];
            #pragma unroll
            for (int nt = 0; nt < 2; nt++)
                acc[j][nt] = __builtin_amdgcn_mfma_f32_16x16x32_bf16(bw[nt], af, acc[j][nt], 0, 0, 0);
        }
    }
    {
        f32x4 bvv[2];
        #pragma unroll
        for (int nt = 0; nt < 2; nt++)
            bvv[nt] = *(const f32x4*)&b2[w * 32 + nt * 16 + quad * 4];
        if constexpr (!THREE) {
            #pragma unroll
            for (int j = 0; j < 4; j++) {
                size_t gm = rowbase + j * 16 + l16;
                if (gm < (size_t)M) {
                    #pragma unroll
                    for (int nt = 0; nt < 2; nt++) {
                        f32x4 v = acc[j][nt] + bvv[nt];
                        uint2 o;
                        o.x = (unsigned)f2bf(v[0]) | ((unsigned)f2bf(v[1]) << 16);
                        o.y = (unsigned)f2bf(v[2]) | ((unsigned)f2bf(v[3]) << 16);
                        *(uint2*)&Cb[gm * 256 + w * 32 + nt * 16 + quad * 4] = o;
                    }
                }
            }
        } else {
            __syncthreads();   // all H reads complete before in-place overwrite
            #pragma unroll
            for (int j = 0; j < 4; j++) {
                int r = j * 16 + l16;
                #pragma unroll
                for (int nt = 0; nt < 2; nt++) {
                    f32x4 v = acc[j][nt] + bvv[nt];
                    int c = w * 4 + nt * 2 + (quad >> 1);
                    int cs = c ^ (r & 7);
                    uint2 o;
                    o.x = (unsigned)f2bf(v[0]) | ((unsigned)f2bf(v[1]) << 16);
                    o.y = (unsigned)f2bf(v[2]) | ((unsigned)f2bf(v[3]) << 16);
                    *(uint2*)&H[r * 256 + cs * 8 + (quad & 1) * 4] = o;
                }
            }
            __syncthreads();
        }
    }

    // ---- phase 3 (THREE only): out = H @ Wo + bo (N=128, fp32) ----
    if constexpr (THREE) {
        f32x4 acc3[4];
        #pragma unroll
        for (int j = 0; j < 4; j++) acc3[j] = (f32x4)(0.f);
        #pragma unroll 2
        for (int ks = 0; ks < 8; ks++) {
            bf16x8 bw = *(const bf16x8*)&W3t[(size_t)(w * 16 + l16) * 256 + ks * 32 + quad * 8];
            #pragma unroll
            for (int j = 0; j < 4; j++) {
                int r = j * 16 + l16;
                int cs = (ks * 4 + quad) ^ (r & 7);
                bf16x8 af = *(const bf16x8*)&H[r * 256 + cs * 8];
                acc3[j] = __builtin_amdgcn_mfma_f32_16x16x32_bf16(bw, af, acc3[j], 0, 0, 0);
            }
        }
        f32x4 bv3 = *(const f32x4*)&b3[w * 16 + quad * 4];
        #pragma unroll
        for (int j = 0; j < 4; j++) {
            size_t gm = rowbase + j * 16 + l16;
            if (gm < (size_t)M) {
                f32x4 v = acc3[j] + bv3;
                *(f32x4*)&Cf[gm * 128 + w * 16 + quad * 4] = v;
            }
        }
    }
}

// ---------------- launch ----------------

static inline size_t align256(size_t v) { return (v + 255) & ~(size_t)255; }

extern "C" void kernel_launch(void* const* d_in, const int* in_sizes, int n_in,
                              void* d_out, int out_size, void* d_ws, size_t ws_size,
                              hipStream_t stream) {
    const float* x        = (const float*)d_in[0];
    const int*   ei       = (const int*)d_in[1];
    const float* eps0     = (const float*)d_in[2];
    const float* W1_0     = (const float*)d_in[3];
    const float* b1_0     = (const float*)d_in[4];
    const float* W2_0     = (const float*)d_in[5];
    const float* b2_0     = (const float*)d_in[6];
    const float* eps1     = (const float*)d_in[7];
    const float* W1_1     = (const float*)d_in[8];
    const float* b1_1     = (const float*)d_in[9];
    const float* W2_1     = (const float*)d_in[10];
    const float* b2_1     = (const float*)d_in[11];
    const float* Wo       = (const float*)d_in[12];
    const float* bo       = (const float*)d_in[13];
    float* out            = (float*)d_out;

    const int* srcE = ei;
    const int* dstE = ei + NE;

    char* p = (char*)d_ws;
    size_t o = 0;
    int* cnt  = (int*)(p + o); o = align256(o + (size_t)NN * 4);
    int* srcs = (int*)(p + o); o = align256(o + (size_t)NN * MAXDEG * 4);
    unsigned short* xb   = (unsigned short*)(p + o); o = align256(o + (size_t)NN * DIN * 2);
    unsigned short* w10t = (unsigned short*)(p + o); o = align256(o + (size_t)DHID * DIN * 2);
    unsigned short* w20t = (unsigned short*)(p + o); o = align256(o + (size_t)DHID * DHID * 2);
    unsigned short* w11t = (unsigned short*)(p + o); o = align256(o + (size_t)DHID * DHID * 2);
    unsigned short* w21t = (unsigned short*)(p + o); o = align256(o + (size_t)DHID * DHID * 2);
    unsigned short* wot  = (unsigned short*)(p + o); o = align256(o + (size_t)DIN * DHID * 2);
    unsigned short* bufB = (unsigned short*)(p + o); o = align256(o + (size_t)NN * DHID * 2);

    prep_kernel<<<(NN * DIN / 4 + 255) / 256, 256, 0, stream>>>(
        x, xb, cnt, W1_0, W2_0, W1_1, W2_1, Wo, w10t, w20t, w11t, w21t, wot);
    bucket_kernel<<<(NE / 8 + 255) / 256, 256, 0, stream>>>(srcE, dstE, cnt, srcs, NE);

    int mlpBlocks = (NN + 63) / 64;              // 782

    // layer 0:  xb --[gather+agg+mlp0]--> bufB (bf16, D=256)
    mlp_fused<128, 0><<<mlpBlocks, 512, 0, stream>>>(
        xb, cnt, srcs, eps0, w10t, b1_0, w20t, b2_0, nullptr, nullptr, bufB, nullptr, NN);

    // layer 1 + out:  bufB --[gather+agg+mlp1+o]--> out (fp32, D=128)
    mlp_fused<256, 1><<<mlpBlocks, 512, 0, stream>>>(
        bufB, cnt, srcs, eps1, w11t, b1_1, w21t, b2_1, wot, bo, nullptr, out, NN);
}

// Round 7
// 304.964 us; speedup vs baseline: 1.1854x; 1.0043x over previous
//
#include <hip/hip_runtime.h>

#define NN 50000
#define NE 800000
#define DIN 128
#define DHID 256
#define MAXDEG 128   // Binomial(800k,1/50k): mean 16, sigma 4; 128 = 28 sigma

#define BUCKET_BLOCKS 391   // ceil(800000 / 8 / 256)
#define PREP_BLOCKS 6250    // 50000*128/4 / 256

typedef __bf16 bf16x8 __attribute__((ext_vector_type(8)));
typedef float f32x4 __attribute__((ext_vector_type(4)));

static __device__ __forceinline__ unsigned short f2bf(float f) {
    unsigned u = __float_as_uint(f);
    unsigned r = 0x7fffu + ((u >> 16) & 1u);
    return (unsigned short)((u + r) >> 16);
}
static __device__ __forceinline__ float blo(unsigned u) { return __uint_as_float(u << 16); }
static __device__ __forceinline__ float bhi(unsigned u) { return __uint_as_float(u & 0xffff0000u); }

// ---------------- merged prep + bucket (R7) ----------------
// R6 residual: ~95us outside the two fused dispatches = prep + bucket, serialized.
// They are independent once cnt-zeroing moves to hipMemsetAsync. Merge into one
// kernel (block-range split, bucket blocks first = long pole) so they co-schedule:
// time ~ max(bucket, prep) instead of sum. Also fix prep's weight transpose to
// OUTPUT-linear mapping (k=idx%K): Wt writes perfectly coalesced; W reads stride-N
// line-pulls from L2-resident 1.3MB (reads don't RMW; old write-scatter did 262K
// uncoalesced 2B RMWs). Same per-element values -> bit-identical.

__global__ void prep_bucket_kernel(
        const int* __restrict__ src, const int* __restrict__ dst,
        int* __restrict__ cnt, int* __restrict__ srcs,
        const float* __restrict__ x, unsigned short* __restrict__ xb,
        const float* __restrict__ W1_0, const float* __restrict__ W2_0,
        const float* __restrict__ W1_1, const float* __restrict__ W2_1,
        const float* __restrict__ Wo,
        unsigned short* __restrict__ w10t, unsigned short* __restrict__ w20t,
        unsigned short* __restrict__ w11t, unsigned short* __restrict__ w21t,
        unsigned short* __restrict__ wot) {
    if (blockIdx.x < BUCKET_BLOCKS) {
        // ---- bucket: fixed-stride buckets, x8 edge ILP (verbatim R6) ----
        int i8 = ((int)blockIdx.x * blockDim.x + threadIdx.x) * 8;
        if (i8 >= NE) return;
        int4 da = *(const int4*)&dst[i8];
        int4 db = *(const int4*)&dst[i8 + 4];
        int4 sa = *(const int4*)&src[i8];
        int4 sb = *(const int4*)&src[i8 + 4];
        int t0 = atomicAdd(&cnt[da.x], 1);
        int t1 = atomicAdd(&cnt[da.y], 1);
        int t2 = atomicAdd(&cnt[da.z], 1);
        int t3 = atomicAdd(&cnt[da.w], 1);
        int t4 = atomicAdd(&cnt[db.x], 1);
        int t5 = atomicAdd(&cnt[db.y], 1);
        int t6 = atomicAdd(&cnt[db.z], 1);
        int t7 = atomicAdd(&cnt[db.w], 1);
        if (t0 < MAXDEG) srcs[(size_t)da.x * MAXDEG + t0] = sa.x;
        if (t1 < MAXDEG) srcs[(size_t)da.y * MAXDEG + t1] = sa.y;
        if (t2 < MAXDEG) srcs[(size_t)da.z * MAXDEG + t2] = sa.z;
        if (t3 < MAXDEG) srcs[(size_t)da.w * MAXDEG + t3] = sa.w;
        if (t4 < MAXDEG) srcs[(size_t)db.x * MAXDEG + t4] = sb.x;
        if (t5 < MAXDEG) srcs[(size_t)db.y * MAXDEG + t5] = sb.y;
        if (t6 < MAXDEG) srcs[(size_t)db.z * MAXDEG + t6] = sb.z;
        if (t7 < MAXDEG) srcs[(size_t)db.w * MAXDEG + t7] = sb.w;
    } else {
        // ---- prep: weights transposed (output-linear, coalesced writes) + x->bf16 ----
        int i = ((int)blockIdx.x - BUCKET_BLOCKS) * blockDim.x + threadIdx.x;
        if (i < 262144) {
            const float* W; unsigned short* Wt; int K, N, idx;
            if (i < 32768)        { W = W1_0; Wt = w10t; K = 128; N = 256; idx = i; }
            else if (i < 98304)   { W = W2_0; Wt = w20t; K = 256; N = 256; idx = i - 32768; }
            else if (i < 163840)  { W = W1_1; Wt = w11t; K = 256; N = 256; idx = i - 98304; }
            else if (i < 229376)  { W = W2_1; Wt = w21t; K = 256; N = 256; idx = i - 163840; }
            else                  { W = Wo;   Wt = wot;  K = 256; N = 128; idx = i - 229376; }
            int k = idx % K;   // consecutive idx -> consecutive k -> coalesced Wt write
            int n = idx / K;
            Wt[idx] = f2bf(W[(size_t)k * N + n]);   // Wt[n*K+k] == Wt[idx]
        }
        if (i * 4 < NN * DIN) {
            float4 v = *(const float4*)(x + (size_t)i * 4);
            ushort4 o;
            o.x = f2bf(v.x); o.y = f2bf(v.y); o.z = f2bf(v.z); o.w = f2bf(v.w);
            *(ushort4*)(xb + (size_t)i * 4) = o;
        }
    }
}

// ---------------- fused GIN layer v7 (verbatim R6): 8-wave blocks ----------------
// R5 post-mortem: fusion ~neutral. FETCH 187MB = 7.3x table = 8-XCD L2 duplication
// floor (gather TRAFFIC is irreducible); but fused gather CONCURRENCY was poor:
// occupancy 16.7% (~1.3 blocks/CU) and 8 serial row-passes per wave. v7: 512 threads /
// 8 waves per block. Gather: each wave owns 8 rows (half the serial passes, 2x in-
// flight loads/CU). MLP: R3-verified 8-wave N-split layout (nt=2; same per-block
// W-instruction count, blocks stay 782 -> R1 constraint respected). Phase-0 inner loop
// verbatim from R5 (bit-identical accumulation); MLP phases verbatim from R3.
// A-tile unioned with H in 32KB LDS; A consumed by phase-1 K-loop, extra barrier,
// then H overwrites. XOR 16B-chunk swizzle on A (cs = li ^ (r&7)) and H.

template <int K1, int THREE>
__global__ __launch_bounds__(512) void mlp_fused(
        const unsigned short* __restrict__ X,       // gather table [*, K1] bf16
        const int* __restrict__ cnt, const int* __restrict__ srcs,
        const float* __restrict__ eps_p,
        const unsigned short* __restrict__ W1t, const float* __restrict__ b1,
        const unsigned short* __restrict__ W2t, const float* __restrict__ b2,
        const unsigned short* __restrict__ W3t, const float* __restrict__ b3,
        unsigned short* __restrict__ Cb, float* __restrict__ Cf, int M) {
    constexpr int NKS1 = K1 / 32;
    constexpr int G = (K1 == 128) ? 4 : 2;   // nodes gathered per wave-pass
    constexpr int L = 64 / G;                // lanes per node
    constexpr int RQ = K1 / 8;               // uint4 per row
    __shared__ __align__(16) unsigned short H[64 * 256];   // 32KB union: phase-0 A / H

    const int lane = threadIdx.x & 63;
    const int w = threadIdx.x >> 6;      // wave id 0..7: n-slice / gather row-slice
    const int quad = lane >> 4;
    const int l16 = lane & 15;
    const size_t rowbase = (size_t)blockIdx.x * 64;

    // ---- phase 0: gather-aggregate 64 node rows into LDS (A-layout, swizzled) ----
    {
        const int group = lane / L;
        const int li = lane % L;
        const uint4* xp = (const uint4*)X;
        const float e = 1.0f + eps_p[0];
        #pragma unroll
        for (int p = 0; p < 8 / G; p++) {
            const int r = w * 8 + p * G + group;
            const size_t node = rowbase + r;
            if (node < (size_t)M) {
                int deg = cnt[node]; if (deg > MAXDEG) deg = MAXDEG;
                const int* sp = srcs + (size_t)node * MAXDEG;
                float a[8], b[8];
                #pragma unroll
                for (int j = 0; j < 8; j++) { a[j] = 0.f; b[j] = 0.f; }
                int i = 0;
                for (; i + 8 <= deg; i += 8) {
                    int4 s0 = *(const int4*)&sp[i];
                    int4 s1 = *(const int4*)&sp[i + 4];
                    uint4 v0 = xp[(size_t)s0.x * RQ + li];
                    uint4 v1 = xp[(size_t)s0.y * RQ + li];
                    uint4 v2 = xp[(size_t)s0.z * RQ + li];
                    uint4 v3 = xp[(size_t)s0.w * RQ + li];
                    uint4 v4 = xp[(size_t)s1.x * RQ + li];
                    uint4 v5 = xp[(size_t)s1.y * RQ + li];
                    uint4 v6 = xp[(size_t)s1.z * RQ + li];
                    uint4 v7 = xp[(size_t)s1.w * RQ + li];
                    a[0] += blo(v0.x); a[1] += bhi(v0.x); a[2] += blo(v0.y); a[3] += bhi(v0.y);
                    a[4] += blo(v0.z); a[5] += bhi(v0.z); a[6] += blo(v0.w); a[7] += bhi(v0.w);
                    b[0] += blo(v1.x); b[1] += bhi(v1.x); b[2] += blo(v1.y); b[3] += bhi(v1.y);
                    b[4] += blo(v1.z); b[5] += bhi(v1.z); b[6] += blo(v1.w); b[7] += bhi(v1.w);
                    a[0] += blo(v2.x); a[1] += bhi(v2.x); a[2] += blo(v2.y); a[3] += bhi(v2.y);
                    a[4] += blo(v2.z); a[5] += bhi(v2.z); a[6] += blo(v2.w); a[7] += bhi(v2.w);
                    b[0] += blo(v3.x); b[1] += bhi(v3.x); b[2] += blo(v3.y); b[3] += bhi(v3.y);
                    b[4] += blo(v3.z); b[5] += bhi(v3.z); b[6] += blo(v3.w); b[7] += bhi(v3.w);
                    a[0] += blo(v4.x); a[1] += bhi(v4.x); a[2] += blo(v4.y); a[3] += bhi(v4.y);
                    a[4] += blo(v4.z); a[5] += bhi(v4.z); a[6] += blo(v4.w); a[7] += bhi(v4.w);
                    b[0] += blo(v5.x); b[1] += bhi(v5.x); b[2] += blo(v5.y); b[3] += bhi(v5.y);
                    b[4] += blo(v5.z); b[5] += bhi(v5.z); b[6] += blo(v5.w); b[7] += bhi(v5.w);
                    a[0] += blo(v6.x); a[1] += bhi(v6.x); a[2] += blo(v6.y); a[3] += bhi(v6.y);
                    a[4] += blo(v6.z); a[5] += bhi(v6.z); a[6] += blo(v6.w); a[7] += bhi(v6.w);
                    b[0] += blo(v7.x); b[1] += bhi(v7.x); b[2] += blo(v7.y); b[3] += bhi(v7.y);
                    b[4] += blo(v7.z); b[5] += bhi(v7.z); b[6] += blo(v7.w); b[7] += bhi(v7.w);
                }
                for (; i + 4 <= deg; i += 4) {
                    int4 s = *(const int4*)&sp[i];
                    uint4 v0 = xp[(size_t)s.x * RQ + li];
                    uint4 v1 = xp[(size_t)s.y * RQ + li];
                    uint4 v2 = xp[(size_t)s.z * RQ + li];
                    uint4 v3 = xp[(size_t)s.w * RQ + li];
                    a[0] += blo(v0.x); a[1] += bhi(v0.x); a[2] += blo(v0.y); a[3] += bhi(v0.y);
                    a[4] += blo(v0.z); a[5] += bhi(v0.z); a[6] += blo(v0.w); a[7] += bhi(v0.w);
                    b[0] += blo(v1.x); b[1] += bhi(v1.x); b[2] += blo(v1.y); b[3] += bhi(v1.y);
                    b[4] += blo(v1.z); b[5] += bhi(v1.z); b[6] += blo(v1.w); b[7] += bhi(v1.w);
                    a[0] += blo(v2.x); a[1] += bhi(v2.x); a[2] += blo(v2.y); a[3] += bhi(v2.y);
                    a[4] += blo(v2.z); a[5] += bhi(v2.z); a[6] += blo(v2.w); a[7] += bhi(v2.w);
                    b[0] += blo(v3.x); b[1] += bhi(v3.x); b[2] += blo(v3.y); b[3] += bhi(v3.y);
                    b[4] += blo(v3.z); b[5] += bhi(v3.z); b[6] += blo(v3.w); b[7] += bhi(v3.w);
                }
                for (; i < deg; i++) {
                    uint4 v = xp[(size_t)sp[i] * RQ + li];
                    a[0] += blo(v.x); a[1] += bhi(v.x); a[2] += blo(v.y); a[3] += bhi(v.y);
                    a[4] += blo(v.z); a[5] += bhi(v.z); a[6] += blo(v.w); a[7] += bhi(v.w);
                }
                uint4 xv = xp[(size_t)node * RQ + li];
                a[0] += b[0] + e * blo(xv.x); a[1] += b[1] + e * bhi(xv.x);
                a[2] += b[2] + e * blo(xv.y); a[3] += b[3] + e * bhi(xv.y);
                a[4] += b[4] + e * blo(xv.z); a[5] += b[5] + e * bhi(xv.z);
                a[6] += b[6] + e * blo(xv.w); a[7] += b[7] + e * bhi(xv.w);
                uint4 o;
                o.x = (unsigned)f2bf(a[0]) | ((unsigned)f2bf(a[1]) << 16);
                o.y = (unsigned)f2bf(a[2]) | ((unsigned)f2bf(a[3]) << 16);
                o.z = (unsigned)f2bf(a[4]) | ((unsigned)f2bf(a[5]) << 16);
                o.w = (unsigned)f2bf(a[6]) | ((unsigned)f2bf(a[7]) << 16);
                const int cs = li ^ (r & 7);   // 16B-chunk XOR swizzle (A-layout)
                *(uint4*)&H[r * K1 + cs * 8] = o;
            }
        }
    }
    __syncthreads();

    f32x4 acc[4][2];

    // ---- phase 1: acc = A(LDS) @ W1 (stream W1, 8-wave N-split) ----
    #pragma unroll
    for (int j = 0; j < 4; j++)
        #pragma unroll
        for (int nt = 0; nt < 2; nt++) acc[j][nt] = (f32x4)(0.f);
    #pragma unroll 2
    for (int ks = 0; ks < NKS1; ks++) {
        bf16x8 bw[2];
        #pragma unroll
        for (int nt = 0; nt < 2; nt++)
            bw[nt] = *(const bf16x8*)&W1t[(size_t)(w * 32 + nt * 16 + l16) * K1 + ks * 32 + quad * 8];
        #pragma unroll
        for (int j = 0; j < 4; j++) {
            int r = j * 16 + l16;
            int cs = (ks * 4 + quad) ^ (r & 7);
            bf16x8 af = *(const bf16x8*)&H[r * K1 + cs * 8];
            #pragma unroll
            for (int nt = 0; nt < 2; nt++)
                acc[j][nt] = __builtin_amdgcn_mfma_f32_16x16x32_bf16(bw[nt], af, acc[j][nt], 0, 0, 0);
        }
    }
    __syncthreads();   // A fully consumed by all waves before H overwrites it
    {   // epilogue 1: bias + relu -> H (swizzled)
        f32x4 bvv[2];
        #pragma unroll
        for (int nt = 0; nt < 2; nt++)
            bvv[nt] = *(const f32x4*)&b1[w * 32 + nt * 16 + quad * 4];
        #pragma unroll
        for (int j = 0; j < 4; j++) {
            int r = j * 16 + l16;
            #pragma unroll
            for (int nt = 0; nt < 2; nt++) {
                f32x4 v = acc[j][nt] + bvv[nt];
                v[0] = fmaxf(v[0], 0.f); v[1] = fmaxf(v[1], 0.f);
                v[2] = fmaxf(v[2], 0.f); v[3] = fmaxf(v[3], 0.f);
                int c = w * 4 + nt * 2 + (quad >> 1);
                int cs = c ^ (r & 7);
                uint2 o;
                o.x = (unsigned)f2bf(v[0]) | ((unsigned)f2bf(v[1]) << 16);
                o.y = (unsigned)f2bf(v[2]) | ((unsigned)f2bf(v[3]) << 16);
                *(uint2*)&H[r * 256 + cs * 8 + (quad & 1) * 4] = o;
            }
        }
    }
    __syncthreads();

    // ---- phase 2: acc = H @ W2 (stream W2, K=256) ----
    #pragma unroll
    for (int j = 0; j < 4; j++)
        #pragma unroll
        for (int nt = 0; nt < 2; nt++) acc[j][nt] = (f32x4)(0.f);
    #pragma unroll 2
    for (int ks = 0; ks < 8; ks++) {
        bf16x8 bw[2];
        #pragma unroll
        for (int nt = 0; nt < 2; nt++)
            bw[nt] = *(const bf16x8*)&W2t[(size_t)(w * 32 + nt * 16 + l16) * 256 + ks * 32 + quad * 8];
        #pragma unroll
        for (int j = 0; j < 4; j++) {
            int r = j * 16 + l16;
            int cs = (ks * 4 + quad) ^ (r & 7);
            bf16x8 af = *(const bf16x8*)&H[r * 256 + cs * 8];
            #pragma unroll
            for (int nt = 0; nt < 2; nt++)
                acc[j][nt] = __builtin_amdgcn_mfma_f32_16x16x32_bf16(bw[nt], af, acc[j][nt], 0, 0, 0);
        }
    }
    {
        f32x4 bvv[2];
        #pragma unroll
        for (int nt = 0; nt < 2; nt++)
            bvv[nt] = *(const f32x4*)&b2[w * 32 + nt * 16 + quad * 4];
        if constexpr (!THREE) {
            #pragma unroll
            for (int j = 0; j < 4; j++) {
                size_t gm = rowbase + j * 16 + l16;
                if (gm < (size_t)M) {
                    #pragma unroll
                    for (int nt = 0; nt < 2; nt++) {
                        f32x4 v = acc[j][nt] + bvv[nt];
                        uint2 o;
                        o.x = (unsigned)f2bf(v[0]) | ((unsigned)f2bf(v[1]) << 16);
                        o.y = (unsigned)f2bf(v[2]) | ((unsigned)f2bf(v[3]) << 16);
                        *(uint2*)&Cb[gm * 256 + w * 32 + nt * 16 + quad * 4] = o;
                    }
                }
            }
        } else {
            __syncthreads();   // all H reads complete before in-place overwrite
            #pragma unroll
            for (int j = 0; j < 4; j++) {
                int r = j * 16 + l16;
                #pragma unroll
                for (int nt = 0; nt < 2; nt++) {
                    f32x4 v = acc[j][nt] + bvv[nt];
                    int c = w * 4 + nt * 2 + (quad >> 1);
                    int cs = c ^ (r & 7);
                    uint2 o;
                    o.x = (unsigned)f2bf(v[0]) | ((unsigned)f2bf(v[1]) << 16);
                    o.y = (unsigned)f2bf(v[2]) | ((unsigned)f2bf(v[3]) << 16);
                    *(uint2*)&H[r * 256 + cs * 8 + (quad & 1) * 4] = o;
                }
            }
            __syncthreads();
        }
    }

    // ---- phase 3 (THREE only): out = H @ Wo + bo (N=128, fp32) ----
    if constexpr (THREE) {
        f32x4 acc3[4];
        #pragma unroll
        for (int j = 0; j < 4; j++) acc3[j] = (f32x4)(0.f);
        #pragma unroll 2
        for (int ks = 0; ks < 8; ks++) {
            bf16x8 bw = *(const bf16x8*)&W3t[(size_t)(w * 16 + l16) * 256 + ks * 32 + quad * 8];
            #pragma unroll
            for (int j = 0; j < 4; j++) {
                int r = j * 16 + l16;
                int cs = (ks * 4 + quad) ^ (r & 7);
                bf16x8 af = *(const bf16x8*)&H[r * 256 + cs * 8];
                acc3[j] = __builtin_amdgcn_mfma_f32_16x16x32_bf16(bw, af, acc3[j], 0, 0, 0);
            }
        }
        f32x4 bv3 = *(const f32x4*)&b3[w * 16 + quad * 4];
        #pragma unroll
        for (int j = 0; j < 4; j++) {
            size_t gm = rowbase + j * 16 + l16;
            if (gm < (size_t)M) {
                f32x4 v = acc3[j] + bv3;
                *(f32x4*)&Cf[gm * 128 + w * 16 + quad * 4] = v;
            }
        }
    }
}

// ---------------- launch ----------------

static inline size_t align256(size_t v) { return (v + 255) & ~(size_t)255; }

extern "C" void kernel_launch(void* const* d_in, const int* in_sizes, int n_in,
                              void* d_out, int out_size, void* d_ws, size_t ws_size,
                              hipStream_t stream) {
    const float* x        = (const float*)d_in[0];
    const int*   ei       = (const int*)d_in[1];
    const float* eps0     = (const float*)d_in[2];
    const float* W1_0     = (const float*)d_in[3];
    const float* b1_0     = (const float*)d_in[4];
    const float* W2_0     = (const float*)d_in[5];
    const float* b2_0     = (const float*)d_in[6];
    const float* eps1     = (const float*)d_in[7];
    const float* W1_1     = (const float*)d_in[8];
    const float* b1_1     = (const float*)d_in[9];
    const float* W2_1     = (const float*)d_in[10];
    const float* b2_1     = (const float*)d_in[11];
    const float* Wo       = (const float*)d_in[12];
    const float* bo       = (const float*)d_in[13];
    float* out            = (float*)d_out;

    const int* srcE = ei;
    const int* dstE = ei + NE;

    char* p = (char*)d_ws;
    size_t o = 0;
    int* cnt  = (int*)(p + o); o = align256(o + (size_t)NN * 4);
    int* srcs = (int*)(p + o); o = align256(o + (size_t)NN * MAXDEG * 4);
    unsigned short* xb   = (unsigned short*)(p + o); o = align256(o + (size_t)NN * DIN * 2);
    unsigned short* w10t = (unsigned short*)(p + o); o = align256(o + (size_t)DHID * DIN * 2);
    unsigned short* w20t = (unsigned short*)(p + o); o = align256(o + (size_t)DHID * DHID * 2);
    unsigned short* w11t = (unsigned short*)(p + o); o = align256(o + (size_t)DHID * DHID * 2);
    unsigned short* w21t = (unsigned short*)(p + o); o = align256(o + (size_t)DHID * DHID * 2);
    unsigned short* wot  = (unsigned short*)(p + o); o = align256(o + (size_t)DIN * DHID * 2);
    unsigned short* bufB = (unsigned short*)(p + o); o = align256(o + (size_t)NN * DHID * 2);

    hipMemsetAsync(cnt, 0, (size_t)NN * sizeof(int), stream);
    prep_bucket_kernel<<<BUCKET_BLOCKS + PREP_BLOCKS, 256, 0, stream>>>(
        srcE, dstE, cnt, srcs, x, xb,
        W1_0, W2_0, W1_1, W2_1, Wo, w10t, w20t, w11t, w21t, wot);

    int mlpBlocks = (NN + 63) / 64;              // 782

    // layer 0:  xb --[gather+agg+mlp0]--> bufB (bf16, D=256)
    mlp_fused<128, 0><<<mlpBlocks, 512, 0, stream>>>(
        xb, cnt, srcs, eps0, w10t, b1_0, w20t, b2_0, nullptr, nullptr, bufB, nullptr, NN);

    // layer 1 + out:  bufB --[gather+agg+mlp1+o]--> out (fp32, D=128)
    mlp_fused<256, 1><<<mlpBlocks, 512, 0, stream>>>(
        bufB, cnt, srcs, eps1, w11t, b1_1, w21t, b2_1, wot, bo, nullptr, out, NN);
}